// Round 4
// baseline (421.059 us; speedup 1.0000x reference)
//
#include <hip/hip_runtime.h>
#include <math.h>

#define N_NODES 10000
#define N_EDGES 320000

#define SQRT3F     1.7320508075688772f
#define INV_SQRT3F 0.5773502691896258f
#define INV_SQRT2F 0.7071067811865476f

typedef short bf16x8 __attribute__((ext_vector_type(8)));
typedef short b16x4  __attribute__((ext_vector_type(4)));
typedef float f32x4  __attribute__((ext_vector_type(4)));

static __device__ __forceinline__ unsigned short f2b(float f) {
    unsigned int u = __float_as_uint(f);
    unsigned int r = (u + 0x7fffu + ((u >> 16) & 1u)) >> 16;   // RNE
    return (unsigned short)r;
}
static __device__ __forceinline__ float b2f(unsigned short h) {
    return __uint_as_float(((unsigned int)h) << 16);
}

// ---------------------------------------------------------------------------
// Kernel 0: weights -> bf16, transposed to fragment-friendly [n][k] layout.
// ---------------------------------------------------------------------------
__global__ __launch_bounds__(256) void prep_weights(
    const float* __restrict__ Wfc1, const float* __restrict__ Wfc2,
    unsigned short* __restrict__ W1T, unsigned short* __restrict__ W2T)
{
    int idx = blockIdx.x * 256 + threadIdx.x;
    if (idx < 4096) {
        int n = idx >> 6, k = idx & 63;
        W1T[idx] = f2b(Wfc1[k * 64 + n]);
    } else if (idx < 18432) {
        int j = idx - 4096;
        int n = j >> 6, k = j & 63;
        W2T[j] = f2b(Wfc2[k * 224 + n]);
    }
}

// ---------------------------------------------------------------------------
// Kernel 1: per-node linear transforms into st_vt[n][160]:
//   [0..63]    s_t = nf_s @ W_nl0
//   [64..159]  v_t TRANSPOSED: layout i*32+k  (i spatial, k channel)
// ---------------------------------------------------------------------------
__global__ __launch_bounds__(256) void node_prep(
    const float* __restrict__ nf,
    const float* __restrict__ Wnl0,
    const float* __restrict__ Wnl1,
    float* __restrict__ st_vt)
{
    int gid = blockIdx.x * blockDim.x + threadIdx.x;
    if (gid >= N_NODES * 160) return;
    int n = gid / 160;
    int j = gid - n * 160;
    const float* nfn = nf + (size_t)n * 160;

    float acc = 0.f;
    if (j < 64) {
        #pragma unroll 8
        for (int k = 0; k < 64; ++k) acc += nfn[k] * Wnl0[k * 64 + j];
    } else {
        int t = j - 64;
        int i = t >> 5, k = t & 31;
        #pragma unroll 8
        for (int m = 0; m < 32; ++m) acc += nfn[64 + m * 3 + i] * Wnl1[m * 32 + k];
    }
    st_vt[(size_t)n * 160 + j] = acc;
}

// ---------------------------------------------------------------------------
// Sorting: histogram of src, exclusive scan, scatter to order[].
// ---------------------------------------------------------------------------
__global__ __launch_bounds__(256) void hist_kernel(
    const int* __restrict__ eidx, int* __restrict__ cnt)
{
    int e = blockIdx.x * 256 + threadIdx.x;
    if (e < N_EDGES) atomicAdd(&cnt[eidx[e]], 1);
}

__global__ __launch_bounds__(1024) void scan_kernel(
    const int* __restrict__ cnt, int* __restrict__ row_start)
{
    __shared__ int part[1024];
    const int t = threadIdx.x;
    const int CH = 10;
    int base = t * CH;
    int s = 0;
    for (int i = 0; i < CH; ++i) {
        int idx = base + i;
        if (idx < N_NODES) s += cnt[idx];
    }
    part[t] = s;
    __syncthreads();
    for (int off = 1; off < 1024; off <<= 1) {
        int v = (t >= off) ? part[t - off] : 0;
        __syncthreads();
        part[t] += v;
        __syncthreads();
    }
    int run = (t == 0) ? 0 : part[t - 1];
    for (int i = 0; i < CH; ++i) {
        int idx = base + i;
        if (idx < N_NODES) { row_start[idx] = run; run += cnt[idx]; }
    }
    if (t == 1023) row_start[N_NODES] = run;
}

__global__ __launch_bounds__(256) void scatter_kernel(
    const int* __restrict__ eidx, const int* __restrict__ row_start,
    int* __restrict__ fill, int* __restrict__ order)
{
    int e = blockIdx.x * 256 + threadIdx.x;
    if (e >= N_EDGES) return;
    int s = eidx[e];
    int p = atomicAdd(&fill[s], 1);
    order[row_start[s] + p] = e;
}

// ---------------------------------------------------------------------------
// Kernel 2: MFMA edge MLP + vectorized tensor-product message + seg scatter.
// 256 threads (4 waves), 32 sorted edges per workgroup.
// agg layout (PERMUTED vector regions, i-major):
//   [0:64) out0a | [64:96) out0b | [96:288) out1a: 96+i*64+c
//   [288:384) out1b: 288+i*32+k  | [384:480) out1c: 384+i*32+k
// ---------------------------------------------------------------------------
__global__ __launch_bounds__(256, 4) void edge_conv(
    const float* __restrict__ edge_attr,
    const float* __restrict__ edge_feature,
    const unsigned short* __restrict__ W1T,
    const unsigned short* __restrict__ W2T,
    const int* __restrict__ edge_index,
    const int* __restrict__ order,
    const float* __restrict__ st_vt,
    float* __restrict__ agg)
{
    __shared__ __align__(16) float df_s[32 * 160];       // 20480 B: xs[64] | xvT[3][32]
    __shared__ __align__(16) unsigned short U[32 * 224]; // 14336 B: A1 (first 4KB) then w_s
    __shared__ __align__(16) unsigned short Hs[32 * 64]; // 4096 B
    __shared__ float sh_s[32][3];
    __shared__ int   eid_s[32];
    __shared__ int   src_s[32];
    __shared__ int   dst_s[32];

    unsigned short* A1  = U;   // alive until end of GEMM1
    unsigned short* w_s = U;   // written in GEMM2 (A1 dead)

    const int tid  = threadIdx.x;
    const int lane = tid & 63;
    const int wv   = tid >> 6;   // wave 0..3
    const int l15  = lane & 15;
    const int g    = lane >> 4;  // 0..3

    // ---- phase 0a: edge ids, src/dst, sh1 ----
    if (tid < 32) {
        int e = order[blockIdx.x * 32 + tid];
        eid_s[tid] = e;
        src_s[tid] = edge_index[e];
        dst_s[tid] = edge_index[N_EDGES + e];
        float x = edge_attr[(size_t)e * 3 + 0];
        float y = edge_attr[(size_t)e * 3 + 1];
        float z = edge_attr[(size_t)e * 3 + 2];
        float inv = SQRT3F / sqrtf(x * x + y * y + z * z);
        sh_s[tid][0] = x * inv;
        sh_s[tid][1] = y * inv;
        sh_s[tid][2] = z * inv;
    }
    __syncthreads();

    // ---- phase 0b: vectorized gathers ----
    // ef: 512 float4-quads -> bf16, swizzled A1
    #pragma unroll
    for (int r = 0; r < 2; ++r) {
        int q = tid + r * 256;
        int e = q >> 4, qf = q & 15;
        int f0 = qf * 4;
        f32x4 v = *reinterpret_cast<const f32x4*>(
            edge_feature + (size_t)eid_s[e] * 64 + f0);
        b16x4 h;
        #pragma unroll
        for (int j = 0; j < 4; ++j) h[j] = (short)f2b(v[j]);
        *reinterpret_cast<b16x4*>(&A1[e * 64 + (f0 ^ ((e & 7) << 3))]) = h;
    }
    // df: 1280 float4-quads from st_vt (already transposed layout)
    #pragma unroll
    for (int r = 0; r < 5; ++r) {
        int q = tid + r * 256;
        int e = q / 40, qf = q - e * 40;
        f32x4 v = *reinterpret_cast<const f32x4*>(
            st_vt + (size_t)dst_s[e] * 160 + qf * 4);
        *reinterpret_cast<f32x4*>(&df_s[e * 160 + qf * 4]) = v;
    }
    __syncthreads();

    // ---- GEMM1: Hs = relu(A1 @ Wfc1), wave wv owns n-strip nt=wv ----
    {
        const int nt = wv;
        bf16x8 b0 = *reinterpret_cast<const bf16x8*>(&W1T[(nt * 16 + l15) * 64 + g * 8]);
        bf16x8 b1 = *reinterpret_cast<const bf16x8*>(&W1T[(nt * 16 + l15) * 64 + 32 + g * 8]);
        #pragma unroll
        for (int mt = 0; mt < 2; ++mt) {
            f32x4 acc = {0.f, 0.f, 0.f, 0.f};
            int ra = mt * 16 + l15;
            int sw = (ra & 7) << 3;
            bf16x8 a0 = *reinterpret_cast<const bf16x8*>(&A1[ra * 64 + ((g * 8) ^ sw)]);
            bf16x8 a1 = *reinterpret_cast<const bf16x8*>(&A1[ra * 64 + ((32 + g * 8) ^ sw)]);
            acc = __builtin_amdgcn_mfma_f32_16x16x32_bf16(a0, b0, acc, 0, 0, 0);
            acc = __builtin_amdgcn_mfma_f32_16x16x32_bf16(a1, b1, acc, 0, 0, 0);
            #pragma unroll
            for (int r = 0; r < 4; ++r) {
                int row = mt * 16 + g * 4 + r;
                int col = nt * 16 + l15;
                Hs[row * 64 + (col ^ ((row & 7) << 3))] = f2b(fmaxf(acc[r], 0.f));
            }
        }
    }
    __syncthreads();

    // ---- GEMM2: w_s = Hs @ Wfc2 (overwrites U; A1 dead) ----
    {
        int ntn = (wv < 2) ? 4 : 3;
        int nt0 = wv * 4 - ((wv == 3) ? 1 : 0);
        for (int ii = 0; ii < ntn; ++ii) {
            int nt = nt0 + ii;
            bf16x8 b0 = *reinterpret_cast<const bf16x8*>(&W2T[(nt * 16 + l15) * 64 + g * 8]);
            bf16x8 b1 = *reinterpret_cast<const bf16x8*>(&W2T[(nt * 16 + l15) * 64 + 32 + g * 8]);
            #pragma unroll
            for (int mt = 0; mt < 2; ++mt) {
                f32x4 acc = {0.f, 0.f, 0.f, 0.f};
                int ra = mt * 16 + l15;
                int sw = (ra & 7) << 3;
                bf16x8 a0 = *reinterpret_cast<const bf16x8*>(&Hs[ra * 64 + ((g * 8) ^ sw)]);
                bf16x8 a1 = *reinterpret_cast<const bf16x8*>(&Hs[ra * 64 + ((32 + g * 8) ^ sw)]);
                acc = __builtin_amdgcn_mfma_f32_16x16x32_bf16(a0, b0, acc, 0, 0, 0);
                acc = __builtin_amdgcn_mfma_f32_16x16x32_bf16(a1, b1, acc, 0, 0, 0);
                #pragma unroll
                for (int r = 0; r < 4; ++r) {
                    int row = mt * 16 + g * 4 + r;
                    w_s[row * 224 + nt * 16 + l15] = f2b(acc[r]);
                }
            }
        }
    }
    __syncthreads();

    // ---- phase 3: vectorized messages, register-accumulated per segment ----
    {
        const int tid2 = tid & 127;
        const int eBeg = (tid >> 7) * 16;   // waves 0-1: edges 0-15; 2-3: 16-31

        int region, cb, iv;
        if (tid2 < 48)       { region = 0; cb = tid2 & 15;        iv = tid2 >> 4; }        // 1a
        else if (tid2 < 64)  { region = 1; cb = tid2 - 48;        iv = 0; }                // 0a
        else if (tid2 < 88)  { region = 2; cb = (tid2 - 64) & 7;  iv = (tid2 - 64) >> 3; } // 1b
        else if (tid2 < 112) { region = 3; cb = (tid2 - 88) & 7;  iv = (tid2 - 88) >> 3; } // 1c
        else if (tid2 < 120) { region = 4; cb = tid2 - 112;       iv = 0; }                // 0b
        else                 { region = 5; cb = 0; iv = 0; }

        if (region < 5) {
            int base = 0, woff = 0, doff = 0;
            if (region == 0)      { base = 96 + iv * 64 + 4 * cb;  woff = 64 + 4 * cb;  doff = 4 * cb; }
            else if (region == 1) { base = 4 * cb;                 woff = 4 * cb;       doff = 4 * cb; }
            else if (region == 2) { base = 288 + iv * 32 + 4 * cb; woff = 128 + 4 * cb; doff = 64 + iv * 32 + 4 * cb; }
            else if (region == 3) { base = 384 + iv * 32 + 4 * cb; woff = 192 + 4 * cb; }
            else                  { base = 64 + 4 * cb;            woff = 160 + 4 * cb; }
            int i1 = iv + 1; if (i1 == 3) i1 = 0;
            int i2 = 3 - iv - i1;

            f32x4 acc = {0.f, 0.f, 0.f, 0.f};
            int cur = src_s[eBeg];
            #pragma unroll 4
            for (int e = eBeg; e < eBeg + 16; ++e) {
                int s = src_s[e];
                if (s != cur) {
                    #pragma unroll
                    for (int j = 0; j < 4; ++j)
                        atomicAdd(&agg[(size_t)cur * 480 + base + j], acc[j]);
                    acc = (f32x4){0.f, 0.f, 0.f, 0.f};
                    cur = s;
                }
                const float* df = df_s + e * 160;
                const unsigned short* we = w_s + e * 224;
                b16x4 w = *reinterpret_cast<const b16x4*>(we + woff);
                if (region == 0) {
                    f32x4 x = *reinterpret_cast<const f32x4*>(df + doff);
                    float sh = sh_s[e][iv];
                    #pragma unroll
                    for (int j = 0; j < 4; ++j)
                        acc[j] += b2f((unsigned short)w[j]) * x[j] * sh;
                } else if (region == 1) {
                    f32x4 x = *reinterpret_cast<const f32x4*>(df + doff);
                    #pragma unroll
                    for (int j = 0; j < 4; ++j)
                        acc[j] += b2f((unsigned short)w[j]) * x[j];
                } else if (region == 2) {
                    f32x4 x = *reinterpret_cast<const f32x4*>(df + doff);
                    #pragma unroll
                    for (int j = 0; j < 4; ++j)
                        acc[j] += b2f((unsigned short)w[j]) * x[j];
                } else if (region == 3) {
                    f32x4 xA = *reinterpret_cast<const f32x4*>(df + 64 + i1 * 32 + 4 * cb);
                    f32x4 xB = *reinterpret_cast<const f32x4*>(df + 64 + i2 * 32 + 4 * cb);
                    float shA = sh_s[e][i1], shB = sh_s[e][i2];
                    #pragma unroll
                    for (int j = 0; j < 4; ++j)
                        acc[j] += b2f((unsigned short)w[j]) *
                                  (xA[j] * shB - xB[j] * shA) * INV_SQRT2F;
                } else {
                    f32x4 x0 = *reinterpret_cast<const f32x4*>(df + 64 + 4 * cb);
                    f32x4 x1 = *reinterpret_cast<const f32x4*>(df + 96 + 4 * cb);
                    f32x4 x2 = *reinterpret_cast<const f32x4*>(df + 128 + 4 * cb);
                    float s0 = sh_s[e][0], s1 = sh_s[e][1], s2 = sh_s[e][2];
                    #pragma unroll
                    for (int j = 0; j < 4; ++j)
                        acc[j] += b2f((unsigned short)w[j]) *
                                  (x0[j] * s0 + x1[j] * s1 + x2[j] * s2) * INV_SQRT3F;
                }
            }
            #pragma unroll
            for (int j = 0; j < 4; ++j)
                atomicAdd(&agg[(size_t)cur * 480 + base + j], acc[j]);
        }
    }
}

// ---------------------------------------------------------------------------
// Kernel 3: per-node output transform + gating (reads permuted agg layout).
// ---------------------------------------------------------------------------
__global__ __launch_bounds__(128) void out_kernel(
    const float* __restrict__ agg,
    const float* __restrict__ nf,
    const float* __restrict__ Wskip0,
    const float* __restrict__ Wskip1,
    const float* __restrict__ Wout_s,
    const float* __restrict__ Wout_v,
    float* __restrict__ out)
{
    __shared__ float aggl[480];
    __shared__ float os_s[96];
    const int n = blockIdx.x;
    const int tid = threadIdx.x;
    const float* nfn = nf + (size_t)n * 160;

    for (int idx = tid; idx < 480; idx += 128)
        aggl[idx] = agg[(size_t)n * 480 + idx] * (1.f / 32.f);
    __syncthreads();

    if (tid < 96) {
        float acc = 0.f;
        #pragma unroll 8
        for (int k = 0; k < 64; ++k) acc += nfn[k] * Wskip0[k * 96 + tid];
        for (int r = 0; r < 96; ++r) acc += aggl[r] * Wout_s[r * 96 + tid];
        os_s[tid] = acc;
    }
    __syncthreads();

    if (tid < 64) {
        float x = os_s[tid];
        out[(size_t)n * 160 + tid] = x / (1.f + expf(-x));  // silu
    }
    if (tid < 96) {
        int t = tid;
        int k = t / 3, i = t - 3 * k;
        float acc = 0.f;
        #pragma unroll 8
        for (int m = 0; m < 32; ++m) acc += nfn[64 + m * 3 + i] * Wskip1[m * 32 + k];
        // permuted agg: 1a at 96+i*64+c, 1b at 288+i*32+k, 1c at 384+i*32+k
        #pragma unroll 8
        for (int m = 0; m < 64; ++m) acc += aggl[96 + i * 64 + m] * Wout_v[m * 32 + k];
        #pragma unroll 8
        for (int m = 0; m < 32; ++m) acc += aggl[288 + i * 32 + m] * Wout_v[(64 + m) * 32 + k];
        #pragma unroll 8
        for (int m = 0; m < 32; ++m) acc += aggl[384 + i * 32 + m] * Wout_v[(96 + m) * 32 + k];
        float g = os_s[64 + k];
        g = 1.f / (1.f + expf(-g));  // sigmoid gate
        out[(size_t)n * 160 + 64 + t] = g * acc;
    }
}

// ---------------------------------------------------------------------------
extern "C" void kernel_launch(void* const* d_in, const int* in_sizes, int n_in,
                              void* d_out, int out_size, void* d_ws, size_t ws_size,
                              hipStream_t stream)
{
    const float* nf     = (const float*)d_in[0];
    const float* ea     = (const float*)d_in[1];
    const float* ef     = (const float*)d_in[2];
    const float* Wskip0 = (const float*)d_in[3];
    const float* Wskip1 = (const float*)d_in[4];
    const float* Wnl0   = (const float*)d_in[5];
    const float* Wnl1   = (const float*)d_in[6];
    const float* Wfc1   = (const float*)d_in[7];
    const float* Wfc2   = (const float*)d_in[8];
    const float* Wout_s = (const float*)d_in[9];
    const float* Wout_v = (const float*)d_in[10];
    const int*   eidx   = (const int*)d_in[11];
    float* out = (float*)d_out;

    // workspace layout (16B-aligned sections)
    int*   cnt       = (int*)d_ws;                       // 10000
    int*   fill      = cnt + 10000;                      // 10000
    int*   row_start = fill + 10000;                     // 10001 (+pad to 10004)
    int*   order     = row_start + 10004;                // 320000
    float* st_vt     = (float*)(order + 320000);         // 1,600,000
    float* agg       = st_vt + 1600000;                  // 4,800,000
    unsigned short* W1T = (unsigned short*)(agg + 4800000); // 4096
    unsigned short* W2T = W1T + 4096;                       // 14336

    hipMemsetAsync(cnt, 0, 20000 * sizeof(int), stream);               // cnt+fill
    hipMemsetAsync(agg, 0, (size_t)N_NODES * 480 * sizeof(float), stream);

    prep_weights<<<72, 256, 0, stream>>>(Wfc1, Wfc2, W1T, W2T);

    node_prep<<<(N_NODES * 160 + 255) / 256, 256, 0, stream>>>(
        nf, Wnl0, Wnl1, st_vt);

    hist_kernel<<<(N_EDGES + 255) / 256, 256, 0, stream>>>(eidx, cnt);
    scan_kernel<<<1, 1024, 0, stream>>>(cnt, row_start);
    scatter_kernel<<<(N_EDGES + 255) / 256, 256, 0, stream>>>(
        eidx, row_start, fill, order);

    edge_conv<<<N_EDGES / 32, 256, 0, stream>>>(
        ea, ef, W1T, W2T, eidx, order, st_vt, agg);

    out_kernel<<<N_NODES, 128, 0, stream>>>(
        agg, nf, Wskip0, Wskip1, Wout_s, Wout_v, out);
}

// Round 5
// 415.729 us; speedup vs baseline: 1.0128x; 1.0128x over previous
//
#include <hip/hip_runtime.h>
#include <math.h>

#define N_NODES 10000
#define N_EDGES 320000

#define SQRT3F     1.7320508075688772f
#define INV_SQRT3F 0.5773502691896258f
#define INV_SQRT2F 0.7071067811865476f

typedef short bf16x8 __attribute__((ext_vector_type(8)));
typedef short b16x4  __attribute__((ext_vector_type(4)));
typedef float f32x4  __attribute__((ext_vector_type(4)));

static __device__ __forceinline__ unsigned short f2b(float f) {
    unsigned int u = __float_as_uint(f);
    unsigned int r = (u + 0x7fffu + ((u >> 16) & 1u)) >> 16;   // RNE
    return (unsigned short)r;
}
static __device__ __forceinline__ float b2f(unsigned short h) {
    return __uint_as_float(((unsigned int)h) << 16);
}

// ---------------------------------------------------------------------------
// Kernel 0: weights -> bf16, transposed to fragment-friendly [n][k] layout.
// ---------------------------------------------------------------------------
__global__ __launch_bounds__(256) void prep_weights(
    const float* __restrict__ Wfc1, const float* __restrict__ Wfc2,
    unsigned short* __restrict__ W1T, unsigned short* __restrict__ W2T)
{
    int idx = blockIdx.x * 256 + threadIdx.x;
    if (idx < 4096) {
        int n = idx >> 6, k = idx & 63;
        W1T[idx] = f2b(Wfc1[k * 64 + n]);
    } else if (idx < 18432) {
        int j = idx - 4096;
        int n = j >> 6, k = j & 63;
        W2T[j] = f2b(Wfc2[k * 224 + n]);
    }
}

// ---------------------------------------------------------------------------
// Kernel 1: per-node linear transforms into st_vt[n][160]:
//   [0..63]    s_t = nf_s @ W_nl0
//   [64..159]  v_t TRANSPOSED: layout i*32+k  (i spatial, k channel)
// ---------------------------------------------------------------------------
__global__ __launch_bounds__(256) void node_prep(
    const float* __restrict__ nf,
    const float* __restrict__ Wnl0,
    const float* __restrict__ Wnl1,
    float* __restrict__ st_vt)
{
    int gid = blockIdx.x * blockDim.x + threadIdx.x;
    if (gid >= N_NODES * 160) return;
    int n = gid / 160;
    int j = gid - n * 160;
    const float* nfn = nf + (size_t)n * 160;

    float acc = 0.f;
    if (j < 64) {
        #pragma unroll 8
        for (int k = 0; k < 64; ++k) acc += nfn[k] * Wnl0[k * 64 + j];
    } else {
        int t = j - 64;
        int i = t >> 5, k = t & 31;
        #pragma unroll 8
        for (int m = 0; m < 32; ++m) acc += nfn[64 + m * 3 + i] * Wnl1[m * 32 + k];
    }
    st_vt[(size_t)n * 160 + j] = acc;
}

// ---------------------------------------------------------------------------
// Sorting: histogram of src, exclusive scan, scatter to order[].
// ---------------------------------------------------------------------------
__global__ __launch_bounds__(256) void hist_kernel(
    const int* __restrict__ eidx, int* __restrict__ cnt)
{
    int e = blockIdx.x * 256 + threadIdx.x;
    if (e < N_EDGES) atomicAdd(&cnt[eidx[e]], 1);
}

__global__ __launch_bounds__(1024) void scan_kernel(
    const int* __restrict__ cnt, int* __restrict__ row_start)
{
    __shared__ int part[1024];
    const int t = threadIdx.x;
    const int CH = 10;
    int base = t * CH;
    int s = 0;
    for (int i = 0; i < CH; ++i) {
        int idx = base + i;
        if (idx < N_NODES) s += cnt[idx];
    }
    part[t] = s;
    __syncthreads();
    for (int off = 1; off < 1024; off <<= 1) {
        int v = (t >= off) ? part[t - off] : 0;
        __syncthreads();
        part[t] += v;
        __syncthreads();
    }
    int run = (t == 0) ? 0 : part[t - 1];
    for (int i = 0; i < CH; ++i) {
        int idx = base + i;
        if (idx < N_NODES) { row_start[idx] = run; run += cnt[idx]; }
    }
    if (t == 1023) row_start[N_NODES] = run;
}

__global__ __launch_bounds__(256) void scatter_kernel(
    const int* __restrict__ eidx, const int* __restrict__ row_start,
    int* __restrict__ fill, int* __restrict__ order)
{
    int e = blockIdx.x * 256 + threadIdx.x;
    if (e >= N_EDGES) return;
    int s = eidx[e];
    int p = atomicAdd(&fill[s], 1);
    order[row_start[s] + p] = e;
}

// ---------------------------------------------------------------------------
// Kernel 2: MFMA edge MLP + vectorized tensor-product message + seg scatter.
// 256 threads (4 waves), 32 sorted edges per workgroup.
// LDS ~29.4 KB -> 5 blocks/CU (20 waves). df staged in bf16.
// Chunked XCD remap: consecutive sorted tiles share an XCD L2 (atomic locality).
// agg layout (PERMUTED vector regions, i-major):
//   [0:64) out0a | [64:96) out0b | [96:288) out1a: 96+i*64+c
//   [288:384) out1b: 288+i*32+k  | [384:480) out1c: 384+i*32+k
// ---------------------------------------------------------------------------
__global__ __launch_bounds__(256, 5) void edge_conv(
    const float* __restrict__ edge_attr,
    const float* __restrict__ edge_feature,
    const unsigned short* __restrict__ W1T,
    const unsigned short* __restrict__ W2T,
    const int* __restrict__ edge_index,
    const int* __restrict__ order,
    const float* __restrict__ st_vt,
    float* __restrict__ agg)
{
    __shared__ __align__(16) unsigned short df_s[32 * 160]; // 10240 B (bf16)
    __shared__ __align__(16) unsigned short U[32 * 224];    // 14336 B: A1 then w_s
    __shared__ __align__(16) unsigned short Hs[32 * 64];    // 4096 B
    __shared__ float sh_s[32][3];
    __shared__ int   eid_s[32];
    __shared__ int   src_s[32];
    __shared__ int   dst_s[32];

    unsigned short* A1  = U;   // alive until end of GEMM1
    unsigned short* w_s = U;   // written in GEMM2 (A1 dead)

    // chunked XCD remap (10000 = 8 * 1250, bijective)
    const int bid = (blockIdx.x & 7) * 1250 + (blockIdx.x >> 3);

    const int tid  = threadIdx.x;
    const int lane = tid & 63;
    const int wv   = tid >> 6;   // wave 0..3
    const int l15  = lane & 15;
    const int g    = lane >> 4;  // 0..3

    // ---- phase 0a: edge ids, src/dst, sh1 ----
    if (tid < 32) {
        int e = order[bid * 32 + tid];
        eid_s[tid] = e;
        src_s[tid] = edge_index[e];
        dst_s[tid] = edge_index[N_EDGES + e];
        float x = edge_attr[(size_t)e * 3 + 0];
        float y = edge_attr[(size_t)e * 3 + 1];
        float z = edge_attr[(size_t)e * 3 + 2];
        float inv = SQRT3F / sqrtf(x * x + y * y + z * z);
        sh_s[tid][0] = x * inv;
        sh_s[tid][1] = y * inv;
        sh_s[tid][2] = z * inv;
    }
    __syncthreads();

    // ---- phase 0b: vectorized gathers (f32x4 in, bf16 out) ----
    // ef: 512 float4-quads -> bf16, swizzled A1
    #pragma unroll
    for (int r = 0; r < 2; ++r) {
        int q = tid + r * 256;
        int e = q >> 4, qf = q & 15;
        int f0 = qf * 4;
        f32x4 v = *reinterpret_cast<const f32x4*>(
            edge_feature + (size_t)eid_s[e] * 64 + f0);
        b16x4 h;
        #pragma unroll
        for (int j = 0; j < 4; ++j) h[j] = (short)f2b(v[j]);
        *reinterpret_cast<b16x4*>(&A1[e * 64 + (f0 ^ ((e & 7) << 3))]) = h;
    }
    // df: 1280 float4-quads from st_vt -> bf16
    #pragma unroll
    for (int r = 0; r < 5; ++r) {
        int q = tid + r * 256;
        int e = q / 40, qf = q - e * 40;
        f32x4 v = *reinterpret_cast<const f32x4*>(
            st_vt + (size_t)dst_s[e] * 160 + qf * 4);
        b16x4 h;
        #pragma unroll
        for (int j = 0; j < 4; ++j) h[j] = (short)f2b(v[j]);
        *reinterpret_cast<b16x4*>(&df_s[e * 160 + qf * 4]) = h;
    }
    __syncthreads();

    // ---- GEMM1: Hs = relu(A1 @ Wfc1), wave wv owns n-strip nt=wv ----
    {
        const int nt = wv;
        bf16x8 b0 = *reinterpret_cast<const bf16x8*>(&W1T[(nt * 16 + l15) * 64 + g * 8]);
        bf16x8 b1 = *reinterpret_cast<const bf16x8*>(&W1T[(nt * 16 + l15) * 64 + 32 + g * 8]);
        #pragma unroll
        for (int mt = 0; mt < 2; ++mt) {
            f32x4 acc = {0.f, 0.f, 0.f, 0.f};
            int ra = mt * 16 + l15;
            int sw = (ra & 7) << 3;
            bf16x8 a0 = *reinterpret_cast<const bf16x8*>(&A1[ra * 64 + ((g * 8) ^ sw)]);
            bf16x8 a1 = *reinterpret_cast<const bf16x8*>(&A1[ra * 64 + ((32 + g * 8) ^ sw)]);
            acc = __builtin_amdgcn_mfma_f32_16x16x32_bf16(a0, b0, acc, 0, 0, 0);
            acc = __builtin_amdgcn_mfma_f32_16x16x32_bf16(a1, b1, acc, 0, 0, 0);
            #pragma unroll
            for (int r = 0; r < 4; ++r) {
                int row = mt * 16 + g * 4 + r;
                int col = nt * 16 + l15;
                Hs[row * 64 + (col ^ ((row & 7) << 3))] = f2b(fmaxf(acc[r], 0.f));
            }
        }
    }
    __syncthreads();

    // ---- GEMM2: w_s = Hs @ Wfc2 (overwrites U; A1 dead) ----
    {
        int ntn = (wv < 2) ? 4 : 3;
        int nt0 = wv * 4 - ((wv == 3) ? 1 : 0);
        for (int ii = 0; ii < ntn; ++ii) {
            int nt = nt0 + ii;
            bf16x8 b0 = *reinterpret_cast<const bf16x8*>(&W2T[(nt * 16 + l15) * 64 + g * 8]);
            bf16x8 b1 = *reinterpret_cast<const bf16x8*>(&W2T[(nt * 16 + l15) * 64 + 32 + g * 8]);
            #pragma unroll
            for (int mt = 0; mt < 2; ++mt) {
                f32x4 acc = {0.f, 0.f, 0.f, 0.f};
                int ra = mt * 16 + l15;
                int sw = (ra & 7) << 3;
                bf16x8 a0 = *reinterpret_cast<const bf16x8*>(&Hs[ra * 64 + ((g * 8) ^ sw)]);
                bf16x8 a1 = *reinterpret_cast<const bf16x8*>(&Hs[ra * 64 + ((32 + g * 8) ^ sw)]);
                acc = __builtin_amdgcn_mfma_f32_16x16x32_bf16(a0, b0, acc, 0, 0, 0);
                acc = __builtin_amdgcn_mfma_f32_16x16x32_bf16(a1, b1, acc, 0, 0, 0);
                #pragma unroll
                for (int r = 0; r < 4; ++r) {
                    int row = mt * 16 + g * 4 + r;
                    w_s[row * 224 + nt * 16 + l15] = f2b(acc[r]);
                }
            }
        }
    }
    __syncthreads();

    // ---- phase 3: vectorized messages, register-accumulated per segment ----
    {
        const int tid2 = tid & 127;
        const int eBeg = (tid >> 7) * 16;   // waves 0-1: edges 0-15; 2-3: 16-31

        int region, cb, iv;
        if (tid2 < 48)       { region = 0; cb = tid2 & 15;        iv = tid2 >> 4; }        // 1a
        else if (tid2 < 64)  { region = 1; cb = tid2 - 48;        iv = 0; }                // 0a
        else if (tid2 < 88)  { region = 2; cb = (tid2 - 64) & 7;  iv = (tid2 - 64) >> 3; } // 1b
        else if (tid2 < 112) { region = 3; cb = (tid2 - 88) & 7;  iv = (tid2 - 88) >> 3; } // 1c
        else if (tid2 < 120) { region = 4; cb = tid2 - 112;       iv = 0; }                // 0b
        else                 { region = 5; cb = 0; iv = 0; }

        if (region < 5) {
            int base = 0, woff = 0, doff = 0;
            if (region == 0)      { base = 96 + iv * 64 + 4 * cb;  woff = 64 + 4 * cb;  doff = 4 * cb; }
            else if (region == 1) { base = 4 * cb;                 woff = 4 * cb;       doff = 4 * cb; }
            else if (region == 2) { base = 288 + iv * 32 + 4 * cb; woff = 128 + 4 * cb; doff = 64 + iv * 32 + 4 * cb; }
            else if (region == 3) { base = 384 + iv * 32 + 4 * cb; woff = 192 + 4 * cb; }
            else                  { base = 64 + 4 * cb;            woff = 160 + 4 * cb; }
            int i1 = iv + 1; if (i1 == 3) i1 = 0;
            int i2 = 3 - iv - i1;

            f32x4 acc = {0.f, 0.f, 0.f, 0.f};
            int cur = src_s[eBeg];
            #pragma unroll 4
            for (int e = eBeg; e < eBeg + 16; ++e) {
                int s = src_s[e];
                if (s != cur) {
                    #pragma unroll
                    for (int j = 0; j < 4; ++j)
                        atomicAdd(&agg[(size_t)cur * 480 + base + j], acc[j]);
                    acc = (f32x4){0.f, 0.f, 0.f, 0.f};
                    cur = s;
                }
                const unsigned short* df = df_s + e * 160;
                const unsigned short* we = w_s + e * 224;
                b16x4 w = *reinterpret_cast<const b16x4*>(we + woff);
                if (region == 0) {
                    b16x4 x = *reinterpret_cast<const b16x4*>(df + doff);
                    float sh = sh_s[e][iv];
                    #pragma unroll
                    for (int j = 0; j < 4; ++j)
                        acc[j] += b2f((unsigned short)w[j]) * b2f((unsigned short)x[j]) * sh;
                } else if (region == 1) {
                    b16x4 x = *reinterpret_cast<const b16x4*>(df + doff);
                    #pragma unroll
                    for (int j = 0; j < 4; ++j)
                        acc[j] += b2f((unsigned short)w[j]) * b2f((unsigned short)x[j]);
                } else if (region == 2) {
                    b16x4 x = *reinterpret_cast<const b16x4*>(df + doff);
                    #pragma unroll
                    for (int j = 0; j < 4; ++j)
                        acc[j] += b2f((unsigned short)w[j]) * b2f((unsigned short)x[j]);
                } else if (region == 3) {
                    b16x4 xA = *reinterpret_cast<const b16x4*>(df + 64 + i1 * 32 + 4 * cb);
                    b16x4 xB = *reinterpret_cast<const b16x4*>(df + 64 + i2 * 32 + 4 * cb);
                    float shA = sh_s[e][i1], shB = sh_s[e][i2];
                    #pragma unroll
                    for (int j = 0; j < 4; ++j)
                        acc[j] += b2f((unsigned short)w[j]) *
                                  (b2f((unsigned short)xA[j]) * shB -
                                   b2f((unsigned short)xB[j]) * shA) * INV_SQRT2F;
                } else {
                    b16x4 x0 = *reinterpret_cast<const b16x4*>(df + 64 + 4 * cb);
                    b16x4 x1 = *reinterpret_cast<const b16x4*>(df + 96 + 4 * cb);
                    b16x4 x2 = *reinterpret_cast<const b16x4*>(df + 128 + 4 * cb);
                    float s0 = sh_s[e][0], s1 = sh_s[e][1], s2 = sh_s[e][2];
                    #pragma unroll
                    for (int j = 0; j < 4; ++j)
                        acc[j] += b2f((unsigned short)w[j]) *
                                  (b2f((unsigned short)x0[j]) * s0 +
                                   b2f((unsigned short)x1[j]) * s1 +
                                   b2f((unsigned short)x2[j]) * s2) * INV_SQRT3F;
                }
            }
            #pragma unroll
            for (int j = 0; j < 4; ++j)
                atomicAdd(&agg[(size_t)cur * 480 + base + j], acc[j]);
        }
    }
}

// ---------------------------------------------------------------------------
// Kernel 3: per-node output transform + gating (reads permuted agg layout).
// ---------------------------------------------------------------------------
__global__ __launch_bounds__(128) void out_kernel(
    const float* __restrict__ agg,
    const float* __restrict__ nf,
    const float* __restrict__ Wskip0,
    const float* __restrict__ Wskip1,
    const float* __restrict__ Wout_s,
    const float* __restrict__ Wout_v,
    float* __restrict__ out)
{
    __shared__ float aggl[480];
    __shared__ float os_s[96];
    const int n = blockIdx.x;
    const int tid = threadIdx.x;
    const float* nfn = nf + (size_t)n * 160;

    for (int idx = tid; idx < 480; idx += 128)
        aggl[idx] = agg[(size_t)n * 480 + idx] * (1.f / 32.f);
    __syncthreads();

    if (tid < 96) {
        float acc = 0.f;
        #pragma unroll 8
        for (int k = 0; k < 64; ++k) acc += nfn[k] * Wskip0[k * 96 + tid];
        for (int r = 0; r < 96; ++r) acc += aggl[r] * Wout_s[r * 96 + tid];
        os_s[tid] = acc;
    }
    __syncthreads();

    if (tid < 64) {
        float x = os_s[tid];
        out[(size_t)n * 160 + tid] = x / (1.f + expf(-x));  // silu
    }
    if (tid < 96) {
        int t = tid;
        int k = t / 3, i = t - 3 * k;
        float acc = 0.f;
        #pragma unroll 8
        for (int m = 0; m < 32; ++m) acc += nfn[64 + m * 3 + i] * Wskip1[m * 32 + k];
        // permuted agg: 1a at 96+i*64+c, 1b at 288+i*32+k, 1c at 384+i*32+k
        #pragma unroll 8
        for (int m = 0; m < 64; ++m) acc += aggl[96 + i * 64 + m] * Wout_v[m * 32 + k];
        #pragma unroll 8
        for (int m = 0; m < 32; ++m) acc += aggl[288 + i * 32 + m] * Wout_v[(64 + m) * 32 + k];
        #pragma unroll 8
        for (int m = 0; m < 32; ++m) acc += aggl[384 + i * 32 + m] * Wout_v[(96 + m) * 32 + k];
        float g = os_s[64 + k];
        g = 1.f / (1.f + expf(-g));  // sigmoid gate
        out[(size_t)n * 160 + 64 + t] = g * acc;
    }
}

// ---------------------------------------------------------------------------
extern "C" void kernel_launch(void* const* d_in, const int* in_sizes, int n_in,
                              void* d_out, int out_size, void* d_ws, size_t ws_size,
                              hipStream_t stream)
{
    const float* nf     = (const float*)d_in[0];
    const float* ea     = (const float*)d_in[1];
    const float* ef     = (const float*)d_in[2];
    const float* Wskip0 = (const float*)d_in[3];
    const float* Wskip1 = (const float*)d_in[4];
    const float* Wnl0   = (const float*)d_in[5];
    const float* Wnl1   = (const float*)d_in[6];
    const float* Wfc1   = (const float*)d_in[7];
    const float* Wfc2   = (const float*)d_in[8];
    const float* Wout_s = (const float*)d_in[9];
    const float* Wout_v = (const float*)d_in[10];
    const int*   eidx   = (const int*)d_in[11];
    float* out = (float*)d_out;

    // workspace layout (16B-aligned sections)
    int*   cnt       = (int*)d_ws;                       // 10000
    int*   fill      = cnt + 10000;                      // 10000
    int*   row_start = fill + 10000;                     // 10001 (+pad to 10004)
    int*   order     = row_start + 10004;                // 320000
    float* st_vt     = (float*)(order + 320000);         // 1,600,000
    float* agg       = st_vt + 1600000;                  // 4,800,000
    unsigned short* W1T = (unsigned short*)(agg + 4800000); // 4096
    unsigned short* W2T = W1T + 4096;                       // 14336

    hipMemsetAsync(cnt, 0, 20000 * sizeof(int), stream);               // cnt+fill
    hipMemsetAsync(agg, 0, (size_t)N_NODES * 480 * sizeof(float), stream);

    prep_weights<<<72, 256, 0, stream>>>(Wfc1, Wfc2, W1T, W2T);

    node_prep<<<(N_NODES * 160 + 255) / 256, 256, 0, stream>>>(
        nf, Wnl0, Wnl1, st_vt);

    hist_kernel<<<(N_EDGES + 255) / 256, 256, 0, stream>>>(eidx, cnt);
    scan_kernel<<<1, 1024, 0, stream>>>(cnt, row_start);
    scatter_kernel<<<(N_EDGES + 255) / 256, 256, 0, stream>>>(
        eidx, row_start, fill, order);

    edge_conv<<<N_EDGES / 32, 256, 0, stream>>>(
        ea, ef, W1T, W2T, eidx, order, st_vt, agg);

    out_kernel<<<N_NODES, 128, 0, stream>>>(
        agg, nf, Wskip0, Wskip1, Wout_s, Wout_v, out);
}

// Round 6
// 339.179 us; speedup vs baseline: 1.2414x; 1.2257x over previous
//
#include <hip/hip_runtime.h>
#include <math.h>

#define N_NODES 10000
#define N_EDGES 320000
#define TILES 5                 // 5 tiles x 32 edges = 160 edges per block
#define NBLK (N_EDGES / (32 * TILES))   // 2000 blocks

#define SQRT3F     1.7320508075688772f
#define INV_SQRT3F 0.5773502691896258f
#define INV_SQRT2F 0.7071067811865476f

typedef short bf16x8 __attribute__((ext_vector_type(8)));
typedef short b16x4  __attribute__((ext_vector_type(4)));
typedef float f32x4  __attribute__((ext_vector_type(4)));
typedef unsigned int u32;

static __device__ __forceinline__ unsigned short f2b(float f) {
    unsigned int u = __float_as_uint(f);
    unsigned int r = (u + 0x7fffu + ((u >> 16) & 1u)) >> 16;   // RNE
    return (unsigned short)r;
}
static __device__ __forceinline__ float b2f(unsigned short h) {
    return __uint_as_float(((unsigned int)h) << 16);
}

// direct global->LDS 16B copy (wave-uniform LDS base + lane*16; per-lane global src)
static __device__ __forceinline__ void gl_lds16(const void* g, void* l) {
    __builtin_amdgcn_global_load_lds(
        (const __attribute__((address_space(1))) u32*)g,
        (__attribute__((address_space(3))) u32*)l,
        16, 0, 0);
}

// ---------------------------------------------------------------------------
// Kernel 0: weights -> bf16, transposed to fragment-friendly [n][k] layout.
// ---------------------------------------------------------------------------
__global__ __launch_bounds__(256) void prep_weights(
    const float* __restrict__ Wfc1, const float* __restrict__ Wfc2,
    unsigned short* __restrict__ W1T, unsigned short* __restrict__ W2T)
{
    int idx = blockIdx.x * 256 + threadIdx.x;
    if (idx < 4096) {
        int n = idx >> 6, k = idx & 63;
        W1T[idx] = f2b(Wfc1[k * 64 + n]);
    } else if (idx < 18432) {
        int j = idx - 4096;
        int n = j >> 6, k = j & 63;
        W2T[j] = f2b(Wfc2[k * 224 + n]);
    }
}

// ---------------------------------------------------------------------------
// Kernel 1: per-node linear transforms into st_vt16[n][160] (bf16):
//   [0..63]    s_t = nf_s @ W_nl0
//   [64..159]  v_t TRANSPOSED: layout i*32+k
// ---------------------------------------------------------------------------
__global__ __launch_bounds__(256) void node_prep(
    const float* __restrict__ nf,
    const float* __restrict__ Wnl0,
    const float* __restrict__ Wnl1,
    unsigned short* __restrict__ st_vt16)
{
    int gid = blockIdx.x * blockDim.x + threadIdx.x;
    if (gid >= N_NODES * 160) return;
    int n = gid / 160;
    int j = gid - n * 160;
    const float* nfn = nf + (size_t)n * 160;

    float acc = 0.f;
    if (j < 64) {
        #pragma unroll 8
        for (int k = 0; k < 64; ++k) acc += nfn[k] * Wnl0[k * 64 + j];
    } else {
        int t = j - 64;
        int i = t >> 5, k = t & 31;
        #pragma unroll 8
        for (int m = 0; m < 32; ++m) acc += nfn[64 + m * 3 + i] * Wnl1[m * 32 + k];
    }
    st_vt16[(size_t)n * 160 + j] = f2b(acc);
}

// ---------------------------------------------------------------------------
// Sorting: histogram of src, exclusive scan, scatter to sorted arrays.
// scatter also emits src/dst/sh in SORTED order (coalesced reads later).
// ---------------------------------------------------------------------------
__global__ __launch_bounds__(256) void hist_kernel(
    const int* __restrict__ eidx, int* __restrict__ cnt)
{
    int e = blockIdx.x * 256 + threadIdx.x;
    if (e < N_EDGES) atomicAdd(&cnt[eidx[e]], 1);
}

__global__ __launch_bounds__(1024) void scan_kernel(
    const int* __restrict__ cnt, int* __restrict__ row_start)
{
    __shared__ int part[1024];
    const int t = threadIdx.x;
    const int CH = 10;
    int base = t * CH;
    int s = 0;
    for (int i = 0; i < CH; ++i) {
        int idx = base + i;
        if (idx < N_NODES) s += cnt[idx];
    }
    part[t] = s;
    __syncthreads();
    for (int off = 1; off < 1024; off <<= 1) {
        int v = (t >= off) ? part[t - off] : 0;
        __syncthreads();
        part[t] += v;
        __syncthreads();
    }
    int run = (t == 0) ? 0 : part[t - 1];
    for (int i = 0; i < CH; ++i) {
        int idx = base + i;
        if (idx < N_NODES) { row_start[idx] = run; run += cnt[idx]; }
    }
    if (t == 1023) row_start[N_NODES] = run;
}

__global__ __launch_bounds__(256) void scatter_kernel(
    const int* __restrict__ eidx, const float* __restrict__ edge_attr,
    const int* __restrict__ row_start,
    int* __restrict__ fill, int* __restrict__ order,
    int* __restrict__ src_srt, int* __restrict__ dst_srt,
    float* __restrict__ sh_srt)
{
    int e = blockIdx.x * 256 + threadIdx.x;
    if (e >= N_EDGES) return;
    int s = eidx[e];
    int p = atomicAdd(&fill[s], 1) + row_start[s];
    order[p] = e;
    src_srt[p] = s;
    dst_srt[p] = eidx[N_EDGES + e];
    float x = edge_attr[(size_t)e * 3 + 0];
    float y = edge_attr[(size_t)e * 3 + 1];
    float z = edge_attr[(size_t)e * 3 + 2];
    float inv = SQRT3F / sqrtf(x * x + y * y + z * z);
    sh_srt[(size_t)p * 4 + 0] = x * inv;
    sh_srt[(size_t)p * 4 + 1] = y * inv;
    sh_srt[(size_t)p * 4 + 2] = z * inv;
    sh_srt[(size_t)p * 4 + 3] = 0.f;
}

// ---------------------------------------------------------------------------
// Kernel 2: multi-tile MFMA edge MLP + message + segmented scatter.
// 2000 blocks x 256 thr; 5 tiles of 32 sorted edges per block.
// Weights in registers once per block; df via global_load_lds (double-buffered,
// prefetched 1 tile ahead); ef reg-staged prefetched 1 tile ahead.
// ---------------------------------------------------------------------------
__global__ __launch_bounds__(256, 3) void edge_conv(
    const unsigned short* __restrict__ W1T,
    const unsigned short* __restrict__ W2T,
    const int* __restrict__ order,
    const int* __restrict__ src_srt,
    const int* __restrict__ dst_srt,
    const float* __restrict__ sh_srt,
    const float* __restrict__ edge_feature,
    const unsigned short* __restrict__ st_vt16,
    float* __restrict__ agg)
{
    __shared__ __align__(16) unsigned short A1[32 * 64];      // 4 KB (swizzled)
    __shared__ __align__(16) unsigned short Hs[32 * 64];      // 4 KB (swizzled)
    __shared__ __align__(16) unsigned short w_s[32 * 224];    // 14 KB
    __shared__ __align__(16) unsigned short df[2][32 * 160];  // 2 x 10 KB (bf16)
    __shared__ int   eid_s[160];
    __shared__ int   src_s[160];
    __shared__ int   dst_s[160];
    __shared__ float sh_s[160][4];

    const int tid  = threadIdx.x;
    const int lane = tid & 63;
    const int wv   = tid >> 6;
    const int l15  = lane & 15;
    const int g    = lane >> 4;
    const int p0   = blockIdx.x * (32 * TILES);

    // ---- weight fragments (once per block) ----
    bf16x8 w1b0 = *reinterpret_cast<const bf16x8*>(&W1T[(wv * 16 + l15) * 64 + g * 8]);
    bf16x8 w1b1 = *reinterpret_cast<const bf16x8*>(&W1T[(wv * 16 + l15) * 64 + 32 + g * 8]);
    bf16x8 w2b0[4], w2b1[4];
    #pragma unroll
    for (int ii = 0; ii < 4; ++ii) {
        int nt = wv * 4 + ii;    // 0..15 (rows 224..255 of W2T are padding)
        w2b0[ii] = *reinterpret_cast<const bf16x8*>(&W2T[(nt * 16 + l15) * 64 + g * 8]);
        w2b1[ii] = *reinterpret_cast<const bf16x8*>(&W2T[(nt * 16 + l15) * 64 + 32 + g * 8]);
    }

    // ---- block metadata (coalesced, once) ----
    if (tid < 32 * TILES) {
        int p = p0 + tid;
        eid_s[tid] = order[p];
        src_s[tid] = src_srt[p];
        dst_s[tid] = dst_srt[p];
        *reinterpret_cast<f32x4*>(&sh_s[tid][0]) =
            *reinterpret_cast<const f32x4*>(&sh_srt[(size_t)p * 4]);
    }
    __syncthreads();

    // ---- phase-3 region setup (fixed per thread) ----
    const int tid2 = tid & 127;
    int region, cb, iv;
    if (tid2 < 48)       { region = 0; cb = tid2 & 15;        iv = tid2 >> 4; }
    else if (tid2 < 64)  { region = 1; cb = tid2 - 48;        iv = 0; }
    else if (tid2 < 88)  { region = 2; cb = (tid2 - 64) & 7;  iv = (tid2 - 64) >> 3; }
    else if (tid2 < 112) { region = 3; cb = (tid2 - 88) & 7;  iv = (tid2 - 88) >> 3; }
    else if (tid2 < 120) { region = 4; cb = tid2 - 112;       iv = 0; }
    else                 { region = 5; cb = 0; iv = 0; }
    int rbase = 0, woff = 0, doff = 0;
    if (region == 0)      { rbase = 96 + iv * 64 + 4 * cb;  woff = 64 + 4 * cb;  doff = 4 * cb; }
    else if (region == 1) { rbase = 4 * cb;                 woff = 4 * cb;       doff = 4 * cb; }
    else if (region == 2) { rbase = 288 + iv * 32 + 4 * cb; woff = 128 + 4 * cb; doff = 64 + iv * 32 + 4 * cb; }
    else if (region == 3) { rbase = 384 + iv * 32 + 4 * cb; woff = 192 + 4 * cb; }
    else if (region == 4) { rbase = 64 + 4 * cb;            woff = 160 + 4 * cb; }
    int i1 = iv + 1; if (i1 == 3) i1 = 0;
    int i2 = 3 - iv - i1;

    f32x4 acc = {0.f, 0.f, 0.f, 0.f};
    int cur = src_s[(tid >> 7) * 16];

    // ---- staging helpers ----
    f32x4 efr[2];
    auto load_ef = [&](int t) {
        int ebase = t * 32;
        #pragma unroll
        for (int r = 0; r < 2; ++r) {
            int q = tid + r * 256;
            int el = q >> 4, qf = q & 15;
            efr[r] = *reinterpret_cast<const f32x4*>(
                edge_feature + (size_t)eid_s[ebase + el] * 64 + qf * 4);
        }
    };
    auto write_ef = [&]() {
        #pragma unroll
        for (int r = 0; r < 2; ++r) {
            int q = tid + r * 256;
            int el = q >> 4, f0 = (q & 15) * 4;
            b16x4 h;
            #pragma unroll
            for (int j = 0; j < 4; ++j) h[j] = (short)f2b(efr[r][j]);
            *reinterpret_cast<b16x4*>(&A1[el * 64 + (f0 ^ ((el & 7) << 3))]) = h;
        }
    };
    auto issue_df = [&](int t, int b) {
        int ebase = t * 32;
        #pragma unroll
        for (int r = 0; r < 3; ++r) {
            int idx = tid + r * 256;
            if (idx < 640) {                       // waves fully on/off (uniform)
                int el = idx / 20, off = idx - el * 20;
                gl_lds16(st_vt16 + (size_t)dst_s[ebase + el] * 160 + off * 8,
                         &df[b][idx * 8]);
            }
        }
    };

    // ---- prologue: stage tile 0 ----
    issue_df(0, 0);
    load_ef(0);

    for (int t = 0; t < TILES; ++t) {
        const int b = t & 1;

        // A: commit prefetched ef(t) into A1
        write_ef();
        __syncthreads();            // df(t) landed (vmcnt drained), A1 visible

        // C: prefetch tile t+1
        if (t < TILES - 1) {
            issue_df(t + 1, b ^ 1);
            load_ef(t + 1);
        }

        // D: GEMM1  Hs = relu(A1 @ Wfc1)
        {
            const int nt = wv;
            #pragma unroll
            for (int mt = 0; mt < 2; ++mt) {
                f32x4 c4 = {0.f, 0.f, 0.f, 0.f};
                int ra = mt * 16 + l15;
                int sw = (ra & 7) << 3;
                bf16x8 a0 = *reinterpret_cast<const bf16x8*>(&A1[ra * 64 + ((g * 8) ^ sw)]);
                bf16x8 a1 = *reinterpret_cast<const bf16x8*>(&A1[ra * 64 + ((32 + g * 8) ^ sw)]);
                c4 = __builtin_amdgcn_mfma_f32_16x16x32_bf16(a0, w1b0, c4, 0, 0, 0);
                c4 = __builtin_amdgcn_mfma_f32_16x16x32_bf16(a1, w1b1, c4, 0, 0, 0);
                #pragma unroll
                for (int r = 0; r < 4; ++r) {
                    int row = mt * 16 + g * 4 + r;
                    int col = nt * 16 + l15;
                    Hs[row * 64 + (col ^ ((row & 7) << 3))] = f2b(fmaxf(c4[r], 0.f));
                }
            }
        }
        __syncthreads();

        // F: GEMM2  w_s = Hs @ Wfc2 (16 strips unrolled, stores masked nt<14)
        {
            #pragma unroll
            for (int ii = 0; ii < 4; ++ii) {
                int nt = wv * 4 + ii;
                #pragma unroll
                for (int mt = 0; mt < 2; ++mt) {
                    f32x4 c4 = {0.f, 0.f, 0.f, 0.f};
                    int ra = mt * 16 + l15;
                    int sw = (ra & 7) << 3;
                    bf16x8 a0 = *reinterpret_cast<const bf16x8*>(&Hs[ra * 64 + ((g * 8) ^ sw)]);
                    bf16x8 a1 = *reinterpret_cast<const bf16x8*>(&Hs[ra * 64 + ((32 + g * 8) ^ sw)]);
                    c4 = __builtin_amdgcn_mfma_f32_16x16x32_bf16(a0, w2b0[ii], c4, 0, 0, 0);
                    c4 = __builtin_amdgcn_mfma_f32_16x16x32_bf16(a1, w2b1[ii], c4, 0, 0, 0);
                    if (nt < 14) {
                        #pragma unroll
                        for (int r = 0; r < 4; ++r) {
                            int row = mt * 16 + g * 4 + r;
                            w_s[row * 224 + nt * 16 + l15] = f2b(c4[r]);
                        }
                    }
                }
            }
        }
        __syncthreads();

        // H: phase 3 — accumulate messages for tile t, flush on segment change
        if (region < 5) {
            const int e0l = (tid >> 7) * 16;
            #pragma unroll 4
            for (int j2 = 0; j2 < 16; ++j2) {
                int el = e0l + j2;
                int eg = t * 32 + el;
                int s = src_s[eg];
                if (s != cur) {
                    #pragma unroll
                    for (int j = 0; j < 4; ++j)
                        atomicAdd(&agg[(size_t)cur * 480 + rbase + j], acc[j]);
                    acc = (f32x4){0.f, 0.f, 0.f, 0.f};
                    cur = s;
                }
                const unsigned short* dfp = &df[b][el * 160];
                const unsigned short* we  = &w_s[el * 224];
                b16x4 w = *reinterpret_cast<const b16x4*>(we + woff);
                if (region == 0) {
                    b16x4 x = *reinterpret_cast<const b16x4*>(dfp + doff);
                    float sh = sh_s[eg][iv];
                    #pragma unroll
                    for (int j = 0; j < 4; ++j)
                        acc[j] += b2f((unsigned short)w[j]) * b2f((unsigned short)x[j]) * sh;
                } else if (region == 1 || region == 2) {
                    b16x4 x = *reinterpret_cast<const b16x4*>(dfp + doff);
                    #pragma unroll
                    for (int j = 0; j < 4; ++j)
                        acc[j] += b2f((unsigned short)w[j]) * b2f((unsigned short)x[j]);
                } else if (region == 3) {
                    b16x4 xA = *reinterpret_cast<const b16x4*>(dfp + 64 + i1 * 32 + 4 * cb);
                    b16x4 xB = *reinterpret_cast<const b16x4*>(dfp + 64 + i2 * 32 + 4 * cb);
                    float shA = sh_s[eg][i1], shB = sh_s[eg][i2];
                    #pragma unroll
                    for (int j = 0; j < 4; ++j)
                        acc[j] += b2f((unsigned short)w[j]) *
                                  (b2f((unsigned short)xA[j]) * shB -
                                   b2f((unsigned short)xB[j]) * shA) * INV_SQRT2F;
                } else {
                    b16x4 x0 = *reinterpret_cast<const b16x4*>(dfp + 64 + 4 * cb);
                    b16x4 x1 = *reinterpret_cast<const b16x4*>(dfp + 96 + 4 * cb);
                    b16x4 x2 = *reinterpret_cast<const b16x4*>(dfp + 128 + 4 * cb);
                    float s0 = sh_s[eg][0], s1 = sh_s[eg][1], s2 = sh_s[eg][2];
                    #pragma unroll
                    for (int j = 0; j < 4; ++j)
                        acc[j] += b2f((unsigned short)w[j]) *
                                  (b2f((unsigned short)x0[j]) * s0 +
                                   b2f((unsigned short)x1[j]) * s1 +
                                   b2f((unsigned short)x2[j]) * s2) * INV_SQRT3F;
                }
            }
        }
    }

    // epilogue flush
    if (region < 5) {
        #pragma unroll
        for (int j = 0; j < 4; ++j)
            atomicAdd(&agg[(size_t)cur * 480 + rbase + j], acc[j]);
    }
}

// ---------------------------------------------------------------------------
// Kernel 3: per-node output transform + gating (reads permuted agg layout).
// ---------------------------------------------------------------------------
__global__ __launch_bounds__(128) void out_kernel(
    const float* __restrict__ agg,
    const float* __restrict__ nf,
    const float* __restrict__ Wskip0,
    const float* __restrict__ Wskip1,
    const float* __restrict__ Wout_s,
    const float* __restrict__ Wout_v,
    float* __restrict__ out)
{
    __shared__ float aggl[480];
    __shared__ float os_s[96];
    const int n = blockIdx.x;
    const int tid = threadIdx.x;
    const float* nfn = nf + (size_t)n * 160;

    for (int idx = tid; idx < 480; idx += 128)
        aggl[idx] = agg[(size_t)n * 480 + idx] * (1.f / 32.f);
    __syncthreads();

    if (tid < 96) {
        float acc = 0.f;
        #pragma unroll 8
        for (int k = 0; k < 64; ++k) acc += nfn[k] * Wskip0[k * 96 + tid];
        for (int r = 0; r < 96; ++r) acc += aggl[r] * Wout_s[r * 96 + tid];
        os_s[tid] = acc;
    }
    __syncthreads();

    if (tid < 64) {
        float x = os_s[tid];
        out[(size_t)n * 160 + tid] = x / (1.f + expf(-x));  // silu
    }
    if (tid < 96) {
        int t = tid;
        int k = t / 3, i = t - 3 * k;
        float acc = 0.f;
        #pragma unroll 8
        for (int m = 0; m < 32; ++m) acc += nfn[64 + m * 3 + i] * Wskip1[m * 32 + k];
        #pragma unroll 8
        for (int m = 0; m < 64; ++m) acc += aggl[96 + i * 64 + m] * Wout_v[m * 32 + k];
        #pragma unroll 8
        for (int m = 0; m < 32; ++m) acc += aggl[288 + i * 32 + m] * Wout_v[(64 + m) * 32 + k];
        #pragma unroll 8
        for (int m = 0; m < 32; ++m) acc += aggl[384 + i * 32 + m] * Wout_v[(96 + m) * 32 + k];
        float g = os_s[64 + k];
        g = 1.f / (1.f + expf(-g));  // sigmoid gate
        out[(size_t)n * 160 + 64 + t] = g * acc;
    }
}

// ---------------------------------------------------------------------------
extern "C" void kernel_launch(void* const* d_in, const int* in_sizes, int n_in,
                              void* d_out, int out_size, void* d_ws, size_t ws_size,
                              hipStream_t stream)
{
    const float* nf     = (const float*)d_in[0];
    const float* ea     = (const float*)d_in[1];
    const float* ef     = (const float*)d_in[2];
    const float* Wskip0 = (const float*)d_in[3];
    const float* Wskip1 = (const float*)d_in[4];
    const float* Wnl0   = (const float*)d_in[5];
    const float* Wnl1   = (const float*)d_in[6];
    const float* Wfc1   = (const float*)d_in[7];
    const float* Wfc2   = (const float*)d_in[8];
    const float* Wout_s = (const float*)d_in[9];
    const float* Wout_v = (const float*)d_in[10];
    const int*   eidx   = (const int*)d_in[11];
    float* out = (float*)d_out;

    // workspace layout (16B-aligned sections), ~31.5 MB total
    int*   cnt       = (int*)d_ws;                        // 10000
    int*   fill      = cnt + 10000;                       // 10000
    int*   row_start = fill + 10000;                      // 10004
    int*   order     = row_start + 10004;                 // 320000
    int*   src_srt   = order + 320000;                    // 320000
    int*   dst_srt   = src_srt + 320000;                  // 320000
    float* sh_srt    = (float*)(dst_srt + 320000);        // 1,280,000
    float* agg       = sh_srt + 1280000;                  // 4,800,000
    unsigned short* st_vt16 = (unsigned short*)(agg + 4800000); // 1,600,000 shorts
    unsigned short* W1T = st_vt16 + 1600000;              // 4,096 shorts
    unsigned short* W2T = W1T + 4096;                     // 16,384 shorts (256 rows, 224 valid)

    hipMemsetAsync(cnt, 0, 20000 * sizeof(int), stream);               // cnt+fill
    hipMemsetAsync(agg, 0, (size_t)N_NODES * 480 * sizeof(float), stream);

    prep_weights<<<72, 256, 0, stream>>>(Wfc1, Wfc2, W1T, W2T);

    node_prep<<<(N_NODES * 160 + 255) / 256, 256, 0, stream>>>(
        nf, Wnl0, Wnl1, st_vt16);

    hist_kernel<<<(N_EDGES + 255) / 256, 256, 0, stream>>>(eidx, cnt);
    scan_kernel<<<1, 1024, 0, stream>>>(cnt, row_start);
    scatter_kernel<<<(N_EDGES + 255) / 256, 256, 0, stream>>>(
        eidx, ea, row_start, fill, order, src_srt, dst_srt, sh_srt);

    edge_conv<<<NBLK, 256, 0, stream>>>(
        W1T, W2T, order, src_srt, dst_srt, sh_srt, ef, st_vt16, agg);

    out_kernel<<<N_NODES, 128, 0, stream>>>(
        agg, nf, Wskip0, Wskip1, Wout_s, Wout_v, out);
}